// Round 14
// baseline (600.366 us; speedup 1.0000x reference)
//
#include <hip/hip_runtime.h>
#include <stdint.h>

#define HID 64
#define RPB 128          // rows per dst bin
#define TBS 1024         // threads per block for build pass
#define EPT 4            // edges per thread in k_build (registers)
#define CAP 2048         // fixed per-bin-segment capacity (lambda~1279, +21 sigma)
#define MAXBINS 2048     // need 2*NBF <= MAXBINS

typedef __attribute__((ext_vector_type(8))) short bf16x8;
typedef __attribute__((ext_vector_type(4))) float f32x4;

// ---------------------------------------------------------------------------
// bf16 helpers (RTNE pack, cheap unpack).
__device__ inline float bf2f(unsigned short u) {
  return __uint_as_float(((unsigned)u) << 16);
}
__device__ inline unsigned short f2bf(float f) {
  unsigned u = __float_as_uint(f);
  unsigned r = u + 0x7FFFu + ((u >> 16) & 1u);
  return (unsigned short)(r >> 16);
}
__device__ inline unsigned pk2(float a, float b) {
  return (unsigned)f2bf(a) | ((unsigned)f2bf(b) << 16);
}

// ---------------------------------------------------------------------------
// Per-block edge-dtype detect (int64 => all high words of first 1024 values
// are 0; int32 random values make that probability ~0). 4 KB read, L2-hot.
__device__ inline bool detect_is64(const unsigned* __restrict__ eiw, int nWords,
                                   unsigned* shflag, int tid) {
  if (tid == 0) *shflag = 0u;
  __syncthreads();
  if (tid < 1024) {
    int w = 2 * tid + 1;
    unsigned v = (w < nWords) ? eiw[w] : 0u;
    if (v) atomicOr(shflag, 1u);
  }
  __syncthreads();
  return (*shflag == 0u);
}

// ---------------------------------------------------------------------------
// Cursor init: binCursor[i] = i * CAP.
__global__ __launch_bounds__(256) void k_initcur(unsigned* __restrict__ cur,
                                                 int nbins) {
  int i = blockIdx.x * 256 + threadIdx.x;
  if (i < nbins) cur[i] = (unsigned)i * CAP;
}

// ---------------------------------------------------------------------------
// Fused build: blocks < nbb read their 4096-edge chunk ONCE into registers,
// build the LDS bin histogram, claim global per-bin bases via one
// atomicAdd(binCursor[bin], cnt) per (block,bin), then scatter packed
// src|(dlocal<<20) records into the bin's fixed-capacity region.
// Blocks >= nbb compute Mbt/cvec (weight fusion).
__global__ __launch_bounds__(TBS) void k_build(
    const void* __restrict__ eip, const void* __restrict__ ein,
    unsigned* __restrict__ binCursor, unsigned* __restrict__ binned,
    int Ep, int En, int NBF, int nbb,
    const float* __restrict__ Wpos, const float* __restrict__ Wneg,
    const float* __restrict__ Wp, const float* __restrict__ Wn,
    const float* __restrict__ bpos, const float* __restrict__ bneg,
    const float* __restrict__ bp, const float* __restrict__ bn,
    unsigned short* __restrict__ Mbt, float* __restrict__ cvec) {
  const int t = threadIdx.x;
  if ((int)blockIdx.x >= nbb) {
    int idx = ((int)blockIdx.x - nbb) * TBS + t;
    if (idx < 4096) {
      int i = idx >> 6, j = idx & 63;
      float a = 0.f, b = 0.f;
      for (int k = 0; k < 64; ++k) {
        a += Wpos[i * 64 + k] * Wp[k * 64 + j];
        b += Wneg[i * 64 + k] * Wn[k * 64 + j];
      }
      Mbt[j * 64 + i] = f2bf(a);
      Mbt[(64 + j) * 64 + i] = f2bf(b);
    }
    if ((int)blockIdx.x == nbb && t < 64) {
      float acc = bp[t] + bn[t];
      for (int k = 0; k < 64; ++k)
        acc += bpos[k] * Wp[k * 64 + t] + bneg[k] * Wn[k * 64 + t];
      cvec[t] = acc;
    }
    return;
  }
  __shared__ unsigned hist[MAXBINS];
  __shared__ unsigned shflag;
  const int nbins = 2 * NBF;
  for (int i = t; i < nbins; i += TBS) hist[i] = 0u;
  const bool is64 = detect_is64((const unsigned*)eip, 2 * Ep, &shflag, t);
  const long long ET = (long long)Ep + En;
  const long long beg = (long long)blockIdx.x * (EPT * TBS);

  int sr[EPT], dr[EPT];
#pragma unroll
  for (int k = 0; k < EPT; ++k) {
    long long e = beg + (long long)k * TBS + t;
    dr[k] = -1;
    if (e < ET) {
      int seg = e >= Ep;
      long long ee = seg ? e - Ep : e;
      const void* ei = seg ? ein : eip;
      long long Ecur = seg ? En : Ep;
      int s, d;
      if (is64) {
        const long long* p = (const long long*)ei;
        s = (int)p[ee]; d = (int)p[Ecur + ee];
      } else {
        const int* p = (const int*)ei;
        s = p[ee]; d = p[Ecur + ee];
      }
      sr[k] = s;
      dr[k] = seg * NBF * RPB + d;  // encode seg via offset (d < NBF*RPB)
      atomicAdd(&hist[dr[k] >> 7], 1u);
    }
  }
  __syncthreads();
  // Claim global bases; hist[i] becomes this block's running global cursor.
  for (int i = t; i < nbins; i += TBS)
    hist[i] = atomicAdd(&binCursor[i], hist[i]);
  __syncthreads();
#pragma unroll
  for (int k = 0; k < EPT; ++k) {
    if (dr[k] >= 0) {
      int idx = dr[k] >> 7;
      unsigned pos = atomicAdd(&hist[idx], 1u);
      if (pos < (unsigned)(idx + 1) * CAP)  // overflow guard (memory safety)
        binned[pos] = (unsigned)sr[k] | ((unsigned)(dr[k] & 127) << 20);
    }
  }
}

// ---------------------------------------------------------------------------
// Binsort: one block per bin — counting-sort both segments by dlocal into the
// bin-strided CSR; emits per-node [start,end) + dinv.
__global__ __launch_bounds__(512) void k_binsort(
    const unsigned* __restrict__ binned, const unsigned* __restrict__ binCursor,
    unsigned* __restrict__ csr,
    unsigned* __restrict__ offsPb, unsigned* __restrict__ offsPe,
    unsigned* __restrict__ offsNb, unsigned* __restrict__ offsNe,
    float* __restrict__ dinvp, float* __restrict__ dinvn, int N, int NBF) {
  __shared__ unsigned cnt[2 * RPB], sc[2 * RPB], cur[2 * RPB];
  const int t = threadIdx.x;
  const int b = blockIdx.x;
  const unsigned sb0 = (unsigned)b * CAP;
  const unsigned se0 = min(binCursor[b], sb0 + CAP);
  const unsigned sb1 = (unsigned)(NBF + b) * CAP;
  const unsigned se1 = min(binCursor[NBF + b], sb1 + CAP);
  if (t < 2 * RPB) cnt[t] = 0u;
  __syncthreads();
  for (unsigned i = sb0 + t; i < se0; i += 512)
    atomicAdd(&cnt[binned[i] >> 20], 1u);
  for (unsigned i = sb1 + t; i < se1; i += 512)
    atomicAdd(&cnt[RPB + (binned[i] >> 20)], 1u);
  __syncthreads();
  if (t < 2 * RPB) sc[t] = cnt[t];
  __syncthreads();
#pragma unroll
  for (int o = 1; o < RPB; o <<= 1) {
    unsigned v = 0u;
    if (t < 2 * RPB && (t & (RPB - 1)) >= o) v = sc[t - o];
    __syncthreads();
    if (t < 2 * RPB) sc[t] += v;
    __syncthreads();
  }
  if (t < 2 * RPB) {
    unsigned excl = sc[t] - cnt[t];
    int seg = t >> 7;
    unsigned start = (seg ? sb1 : sb0) + excl;
    cur[t] = start;
    int g = b * RPB + (t & (RPB - 1));
    if (g < N) {
      if (seg == 0) {
        offsPb[g] = start;
        offsPe[g] = start + cnt[t];
        dinvp[g] = rsqrtf((float)cnt[t] + 1.0f);
      } else {
        offsNb[g] = start;
        offsNe[g] = start + cnt[t];
        dinvn[g] = rsqrtf((float)cnt[t] + 1.0f);
      }
    }
  }
  __syncthreads();
  for (unsigned i = sb0 + t; i < se0; i += 512) {
    unsigned w = binned[i];
    unsigned p = atomicAdd(&cur[w >> 20], 1u);
    csr[p] = w & 0xFFFFFu;
  }
  for (unsigned i = sb1 + t; i < se1; i += 512) {
    unsigned w = binned[i];
    unsigned p = atomicAdd(&cur[RPB + (w >> 20)], 1u);
    csr[p] = w & 0xFFFFFu;
  }
}

// ---------------------------------------------------------------------------
// Fused LayerNorm + dual GEMM via MFMA (bf16 in, fp32 acc), epilogue scales by
// dinv[row], stores bf16. Block = 256 threads = 4 waves, 64 rows.
__global__ __launch_bounds__(256) void k_ln_gemm(
    const float* __restrict__ h, const float* __restrict__ gamma,
    const float* __restrict__ beta, const unsigned short* __restrict__ Mbt,
    const float* __restrict__ dinvp, const float* __restrict__ dinvn,
    unsigned short* __restrict__ yp, unsigned short* __restrict__ yn, int N) {
  __shared__ __align__(16) unsigned short Abf[64][72];
  __shared__ __align__(16) unsigned short Bt[128][72];
  const int t = threadIdx.x;
  const int r0 = blockIdx.x * 64;

#pragma unroll
  for (int i = 0; i < 4; ++i) {
    int f = i * 256 + t;
    int n = f >> 3, c8 = f & 7;
    *(uint4*)(&Bt[n][c8 * 8]) = ((const uint4*)Mbt)[f];
  }

  const int r = t >> 2, p = t & 3;
  float4 va, vb, vc, vd;
  if (r0 + r < N) {
    const float4* hp = (const float4*)(h + (size_t)(r0 + r) * 64 + p * 16);
    va = hp[0]; vb = hp[1]; vc = hp[2]; vd = hp[3];
  } else {
    va = vb = vc = vd = make_float4(0.f, 0.f, 0.f, 0.f);
  }
  float s  = (va.x + va.y + va.z + va.w) + (vb.x + vb.y + vb.z + vb.w) +
             (vc.x + vc.y + vc.z + vc.w) + (vd.x + vd.y + vd.z + vd.w);
  float ss = (va.x*va.x + va.y*va.y + va.z*va.z + va.w*va.w) +
             (vb.x*vb.x + vb.y*vb.y + vb.z*vb.z + vb.w*vb.w) +
             (vc.x*vc.x + vc.y*vc.y + vc.z*vc.z + vc.w*vc.w) +
             (vd.x*vd.x + vd.y*vd.y + vd.z*vd.z + vd.w*vd.w);
  s  += __shfl_xor(s, 1);  ss += __shfl_xor(ss, 1);
  s  += __shfl_xor(s, 2);  ss += __shfl_xor(ss, 2);
  float mu = s * (1.f / 64.f);
  float var = ss * (1.f / 64.f) - mu * mu;
  float rstd = rsqrtf(var + 1e-5f);
  {
    const float4* g4 = (const float4*)(gamma + p * 16);
    const float4* b4 = (const float4*)(beta + p * 16);
    float4 g0 = g4[0], g1 = g4[1], g2 = g4[2], g3 = g4[3];
    float4 e0 = b4[0], e1 = b4[1], e2 = b4[2], e3 = b4[3];
#define LNV(v, g, e) ((v - mu) * rstd * g + e)
    unsigned w0 = pk2(LNV(va.x, g0.x, e0.x), LNV(va.y, g0.y, e0.y));
    unsigned w1 = pk2(LNV(va.z, g0.z, e0.z), LNV(va.w, g0.w, e0.w));
    unsigned w2 = pk2(LNV(vb.x, g1.x, e1.x), LNV(vb.y, g1.y, e1.y));
    unsigned w3 = pk2(LNV(vb.z, g1.z, e1.z), LNV(vb.w, g1.w, e1.w));
    unsigned w4 = pk2(LNV(vc.x, g2.x, e2.x), LNV(vc.y, g2.y, e2.y));
    unsigned w5 = pk2(LNV(vc.z, g2.z, e2.z), LNV(vc.w, g2.w, e2.w));
    unsigned w6 = pk2(LNV(vd.x, g3.x, e3.x), LNV(vd.y, g3.y, e3.y));
    unsigned w7 = pk2(LNV(vd.z, g3.z, e3.z), LNV(vd.w, g3.w, e3.w));
#undef LNV
    *(uint4*)(&Abf[r][p * 16]) = make_uint4(w0, w1, w2, w3);
    *(uint4*)(&Abf[r][p * 16 + 8]) = make_uint4(w4, w5, w6, w7);
  }
  __syncthreads();

  const int w = t >> 6, lane = t & 63;
  const int mrow = lane & 15, grp = lane >> 4;
  bf16x8 a0 = *(const bf16x8*)(&Abf[w * 16 + mrow][grp * 8]);
  bf16x8 a1 = *(const bf16x8*)(&Abf[w * 16 + mrow][32 + grp * 8]);
  float sp[4], sn[4];
#pragma unroll
  for (int reg = 0; reg < 4; ++reg) {
    int grow = r0 + w * 16 + grp * 4 + reg;
    sp[reg] = (grow < N) ? dinvp[grow] : 0.f;
    sn[reg] = (grow < N) ? dinvn[grow] : 0.f;
  }
#pragma unroll
  for (int ct = 0; ct < 8; ++ct) {
    const int n = ct * 16 + mrow;
    bf16x8 b0 = *(const bf16x8*)(&Bt[n][grp * 8]);
    bf16x8 b1 = *(const bf16x8*)(&Bt[n][32 + grp * 8]);
    f32x4 acc = {0.f, 0.f, 0.f, 0.f};
    acc = __builtin_amdgcn_mfma_f32_16x16x32_bf16(a0, b0, acc, 0, 0, 0);
    acc = __builtin_amdgcn_mfma_f32_16x16x32_bf16(a1, b1, acc, 0, 0, 0);
#pragma unroll
    for (int reg = 0; reg < 4; ++reg) {
      int grow = r0 + w * 16 + grp * 4 + reg;
      if (grow < N) {
        if (ct < 4)
          yp[(size_t)grow * 64 + ct * 16 + mrow] = f2bf(sp[reg] * acc[reg]);
        else
          yn[(size_t)grow * 64 + (ct - 4) * 16 + mrow] = f2bf(sn[reg] * acc[reg]);
      }
    }
  }
}

// ---------------------------------------------------------------------------
// Gather (round-9 proven form): one wave per dst node, FOUR 16-lane groups,
// uint2/lane, 2-deep unroll -> 8 rows in flight. All __shfl execute
// wave-uniformly with clamped source index (ds_bpermute from EXEC-inactive
// source lane is undefined); only loads/accumulates are predicated.
// CSR is bin-strided: per-node [start,end) arrays.
__global__ __launch_bounds__(256) void k_gather(
    const unsigned* __restrict__ offsPb, const unsigned* __restrict__ offsPe,
    const unsigned* __restrict__ offsNb, const unsigned* __restrict__ offsNe,
    const unsigned* __restrict__ csr, const float* __restrict__ dinvp,
    const float* __restrict__ dinvn, const unsigned short* __restrict__ yp,
    const unsigned short* __restrict__ yn, const float* __restrict__ cvec,
    float* __restrict__ out, int N) {
  const int lane = threadIdx.x & 63;
  const int grp = lane >> 4;
  const int lc = lane & 15;
  const int d = (int)(((long long)blockIdx.x * 256 + threadIdx.x) >> 6);
  if (d >= N) return;

  float4 ap = make_float4(0.f, 0.f, 0.f, 0.f);
  float4 an = make_float4(0.f, 0.f, 0.f, 0.f);

#define ACC4(ACC, U)                                                         \
  ACC.x += bf2f((unsigned short)(U.x & 0xFFFFu));                            \
  ACC.y += bf2f((unsigned short)(U.x >> 16));                                \
  ACC.z += bf2f((unsigned short)(U.y & 0xFFFFu));                            \
  ACC.w += bf2f((unsigned short)(U.y >> 16));

#define GATHER_SEG(OFFB, OFFE, Y, ACC)                                       \
  {                                                                          \
    unsigned beg = OFFB[d], end = OFFE[d];                                   \
    for (unsigned base = beg; base < end; base += 64u) {                     \
      int m = (int)min(64u, end - base);                                     \
      int idx = (base + (unsigned)lane < end) ? (int)csr[base + lane] : 0;   \
      int j = 0;                                                             \
      for (; j + 7 < m; j += 8) {                                            \
        int s0 = __shfl(idx, j + grp);                                       \
        int s1 = __shfl(idx, j + 4 + grp);                                   \
        uint2 u0 = *(const uint2*)(Y + (size_t)s0 * 64 + 4 * lc);            \
        uint2 u1 = *(const uint2*)(Y + (size_t)s1 * 64 + 4 * lc);            \
        ACC4(ACC, u0)                                                        \
        ACC4(ACC, u1)                                                        \
      }                                                                      \
      for (; j < m; j += 4) {                                                \
        int e = j + grp;                                                     \
        int es = (e < m) ? e : (m - 1);  /* clamp: source lane stays valid */\
        int s0 = __shfl(idx, es);        /* executed by ALL lanes */         \
        if (e < m) {                                                         \
          uint2 u0 = *(const uint2*)(Y + (size_t)s0 * 64 + 4 * lc);          \
          ACC4(ACC, u0)                                                      \
        }                                                                    \
      }                                                                      \
    }                                                                        \
  }

  GATHER_SEG(offsPb, offsPe, yp, ap)
  GATHER_SEG(offsNb, offsNe, yn, an)
#undef GATHER_SEG

  ap.x += __shfl_xor(ap.x, 16); ap.y += __shfl_xor(ap.y, 16);
  ap.z += __shfl_xor(ap.z, 16); ap.w += __shfl_xor(ap.w, 16);
  an.x += __shfl_xor(an.x, 16); an.y += __shfl_xor(an.y, 16);
  an.z += __shfl_xor(an.z, 16); an.w += __shfl_xor(an.w, 16);
  ap.x += __shfl_xor(ap.x, 32); ap.y += __shfl_xor(ap.y, 32);
  ap.z += __shfl_xor(ap.z, 32); ap.w += __shfl_xor(ap.w, 32);
  an.x += __shfl_xor(an.x, 32); an.y += __shfl_xor(an.y, 32);
  an.z += __shfl_xor(an.z, 32); an.w += __shfl_xor(an.w, 32);

  if (lane < 16) {
    uint2 up = *(const uint2*)(yp + (size_t)d * 64 + 4 * lc);
    uint2 un = *(const uint2*)(yn + (size_t)d * 64 + 4 * lc);
    ap.x += bf2f((unsigned short)(up.x & 0xFFFFu));
    ap.y += bf2f((unsigned short)(up.x >> 16));
    ap.z += bf2f((unsigned short)(up.y & 0xFFFFu));
    ap.w += bf2f((unsigned short)(up.y >> 16));
    an.x += bf2f((unsigned short)(un.x & 0xFFFFu));
    an.y += bf2f((unsigned short)(un.x >> 16));
    an.z += bf2f((unsigned short)(un.y & 0xFFFFu));
    an.w += bf2f((unsigned short)(un.y >> 16));
    float dp = dinvp[d], dn = dinvn[d];
    float4 cc = *(const float4*)(cvec + 4 * lc);
    float4 v;
    v.x = fminf(fmaxf(cc.x + dp * ap.x + dn * an.x, -50.f), 50.f);
    v.y = fminf(fmaxf(cc.y + dp * ap.y + dn * an.y, -50.f), 50.f);
    v.z = fminf(fmaxf(cc.z + dp * ap.z + dn * an.z, -50.f), 50.f);
    v.w = fminf(fmaxf(cc.w + dp * ap.w + dn * an.w, -50.f), 50.f);
    *(float4*)(out + (size_t)d * 64 + 4 * lc) = v;
  }
#undef ACC4
}

// ---------------------------------------------------------------------------
// Fallback path (atomic scatter), bf16 y pre-scaled by dinv[src].
__global__ __launch_bounds__(256) void k_prep(
    const float* __restrict__ Wpos, const float* __restrict__ Wneg,
    const float* __restrict__ Wp, const float* __restrict__ Wn,
    const float* __restrict__ bpos, const float* __restrict__ bneg,
    const float* __restrict__ bp, const float* __restrict__ bn,
    unsigned short* __restrict__ Mbt, float* __restrict__ cvec,
    const unsigned* __restrict__ eiw, unsigned* __restrict__ flag, int nWords) {
  if (blockIdx.x == 16) {
    __shared__ unsigned acc;
    if (threadIdx.x == 0) acc = 0u;
    __syncthreads();
    unsigned bad = 0u;
    for (int i = 0; i < 4; ++i) {
      int w = (i * 256 + (int)threadIdx.x) * 2 + 1;
      if (w < nWords) bad |= eiw[w];
    }
    if (bad) atomicOr(&acc, 1u);
    __syncthreads();
    if (threadIdx.x == 0) *flag = (acc == 0u) ? 1u : 0u;
    return;
  }
  int idx = blockIdx.x * 256 + threadIdx.x;
  int i = idx >> 6, j = idx & 63;
  float a = 0.f, b = 0.f;
  for (int k = 0; k < 64; ++k) {
    a += Wpos[i * 64 + k] * Wp[k * 64 + j];
    b += Wneg[i * 64 + k] * Wn[k * 64 + j];
  }
  Mbt[j * 64 + i] = f2bf(a);
  Mbt[(64 + j) * 64 + i] = f2bf(b);
  if (blockIdx.x == 0 && threadIdx.x < 64) {
    int jj = threadIdx.x;
    float acc = bp[jj] + bn[jj];
    for (int k = 0; k < 64; ++k)
      acc += bpos[k] * Wp[k * 64 + jj] + bneg[k] * Wn[k * 64 + jj];
    cvec[jj] = acc;
  }
}

__global__ __launch_bounds__(256) void k_deg(const void* __restrict__ ei,
                                             const unsigned* __restrict__ flag,
                                             float* __restrict__ deg, int E) {
  int e = blockIdx.x * 256 + threadIdx.x;
  if (e >= E) return;
  long long d;
  if (*flag) d = ((const long long*)ei)[(long long)E + e];
  else       d = (long long)((const int*)ei)[(long long)E + e];
  atomicAdd(&deg[(int)d], 1.0f);
}

__global__ __launch_bounds__(256) void k_dinv(float* __restrict__ degp,
                                              float* __restrict__ degn, int N) {
  int i = blockIdx.x * 256 + threadIdx.x;
  if (i < N) {
    degp[i] = rsqrtf(degp[i] + 1.0f);
    degn[i] = rsqrtf(degn[i] + 1.0f);
  }
}

__global__ __launch_bounds__(256) void k_init_out(
    const unsigned short* __restrict__ yp, const unsigned short* __restrict__ yn,
    const float* __restrict__ dinvp, const float* __restrict__ dinvn,
    const float* __restrict__ cvec, float* __restrict__ out, long long n) {
  long long i = (long long)blockIdx.x * 256 + threadIdx.x;
  if (i >= n) return;
  int row = (int)(i >> 6), col = (int)(i & 63);
  out[i] = cvec[col] + dinvp[row] * bf2f(yp[i]) + dinvn[row] * bf2f(yn[i]);
}

__global__ __launch_bounds__(256) void k_scatter(
    const void* __restrict__ ei, const unsigned* __restrict__ flag,
    const float* __restrict__ dinv, const unsigned short* __restrict__ y,
    float* __restrict__ out, int E) {
  const int lane = threadIdx.x & 63;
  long long e = ((long long)blockIdx.x * 256 + threadIdx.x) >> 6;
  if (e >= E) return;
  long long s, d;
  if (*flag) {
    const long long* p = (const long long*)ei;
    s = p[e]; d = p[E + e];
  } else {
    const int* p = (const int*)ei;
    s = (long long)p[e]; d = (long long)p[E + e];
  }
  float v = dinv[(int)d] * bf2f(y[s * 64 + lane]);
  atomicAdd(out + d * 64 + lane, v);
}

__global__ __launch_bounds__(256) void k_clip(float4* __restrict__ out, int n4) {
  int i = blockIdx.x * 256 + threadIdx.x;
  if (i >= n4) return;
  float4 v = out[i];
  v.x = fminf(fmaxf(v.x, -50.f), 50.f);
  v.y = fminf(fmaxf(v.y, -50.f), 50.f);
  v.z = fminf(fmaxf(v.z, -50.f), 50.f);
  v.w = fminf(fmaxf(v.w, -50.f), 50.f);
  out[i] = v;
}

// ---------------------------------------------------------------------------
extern "C" void kernel_launch(void* const* d_in, const int* in_sizes, int n_in,
                              void* d_out, int out_size, void* d_ws, size_t ws_size,
                              hipStream_t stream) {
  const float* h      = (const float*)d_in[1];
  const void*  ei_pos = d_in[2];
  const void*  ei_neg = d_in[3];
  const float* gamma  = (const float*)d_in[4];
  const float* beta   = (const float*)d_in[5];
  const float* W_pos  = (const float*)d_in[6];
  const float* b_pos  = (const float*)d_in[7];
  const float* W_neg  = (const float*)d_in[8];
  const float* b_neg  = (const float*)d_in[9];
  const float* Wp     = (const float*)d_in[10];
  const float* bp     = (const float*)d_in[11];
  const float* Wn     = (const float*)d_in[12];
  const float* bn     = (const float*)d_in[13];
  float* out = (float*)d_out;

  const int N = in_sizes[1] / HID;
  const int Ep = in_sizes[2] / 2;
  const int En = in_sizes[3] / 2;
  const int NBF = (N + RPB - 1) / RPB;
  const int nbins = 2 * NBF;
  const long long ET = (long long)Ep + En;
  const int nbb = (int)((ET + (long long)EPT * TBS - 1) / ((long long)EPT * TBS));

  float* ws = (float*)d_ws;
  size_t off = 0;
  auto alloc = [&](size_t nf) {
    float* p = ws + off;
    off = (off + nf + 63) & ~(size_t)63;
    return p;
  };
  // Common arrays.
  unsigned short* y_pos = (unsigned short*)alloc((size_t)N * HID / 2);
  unsigned short* y_neg = (unsigned short*)alloc((size_t)N * HID / 2);
  float* dinvp = alloc(N);
  float* dinvn = alloc(N);
  unsigned short* Mbt = (unsigned short*)alloc(128 * 64 / 2);
  float* cvec  = alloc(64);
  unsigned* flag = (unsigned*)alloc(64);
  // Fast-path arrays (fixed-capacity bins; no scan needed).
  unsigned* binCursor = (unsigned*)alloc(nbins);
  unsigned* offsPb = (unsigned*)alloc(N);
  unsigned* offsPe = (unsigned*)alloc(N);
  unsigned* offsNb = (unsigned*)alloc(N);
  unsigned* offsNe = (unsigned*)alloc(N);
  unsigned* binned = (unsigned*)alloc((size_t)nbins * CAP);
  unsigned* csr    = (unsigned*)alloc((size_t)nbins * CAP);
  // Fast path valid if: ws fits, bins fit LDS, avg bin load well under CAP
  // (4x headroom; uniform-random dst => Poisson, CAP margin >> 10 sigma).
  const bool fast = (off * sizeof(float) <= ws_size) && (nbins <= MAXBINS) &&
                    (N < (1 << 20)) &&
                    (ET <= (long long)NBF * (CAP / 2)) && (nbb >= 1);

  if (fast) {
    k_initcur<<<(nbins + 255) / 256, 256, 0, stream>>>(binCursor, nbins);
    k_build<<<nbb + 4, TBS, 0, stream>>>(
        ei_pos, ei_neg, binCursor, binned, Ep, En, NBF, nbb,
        W_pos, W_neg, Wp, Wn, b_pos, b_neg, bp, bn, Mbt, cvec);
    k_binsort<<<NBF, 512, 0, stream>>>(binned, binCursor, csr,
                                       offsPb, offsPe, offsNb, offsNe,
                                       dinvp, dinvn, N, NBF);
    k_ln_gemm<<<(N + 63) / 64, 256, 0, stream>>>(h, gamma, beta, Mbt, dinvp, dinvn,
                                                 y_pos, y_neg, N);
    const long long gthreads = (long long)N * 64;
    k_gather<<<(int)((gthreads + 255) / 256), 256, 0, stream>>>(
        offsPb, offsPe, offsNb, offsNe, csr, dinvp, dinvn,
        y_pos, y_neg, cvec, out, N);
  } else {
    k_prep<<<17, 256, 0, stream>>>(W_pos, W_neg, Wp, Wn, b_pos, b_neg, bp, bn,
                                   Mbt, cvec, (const unsigned*)ei_pos, flag, 2 * Ep);
    hipMemsetAsync(dinvp, 0, sizeof(float) * N, stream);
    hipMemsetAsync(dinvn, 0, sizeof(float) * N, stream);
    k_deg<<<(Ep + 255) / 256, 256, 0, stream>>>(ei_pos, flag, dinvp, Ep);
    k_deg<<<(En + 255) / 256, 256, 0, stream>>>(ei_neg, flag, dinvn, En);
    k_dinv<<<(N + 255) / 256, 256, 0, stream>>>(dinvp, dinvn, N);
    k_ln_gemm<<<(N + 63) / 64, 256, 0, stream>>>(h, gamma, beta, Mbt, dinvp, dinvn,
                                                 y_pos, y_neg, N);
    const long long n = (long long)N * 64;
    k_init_out<<<(int)((n + 255) / 256), 256, 0, stream>>>(y_pos, y_neg, dinvp, dinvn,
                                                           cvec, out, n);
    const long long st = (long long)Ep * 64;
    k_scatter<<<(int)((st + 255) / 256), 256, 0, stream>>>(ei_pos, flag, dinvp, y_pos,
                                                           out, Ep);
    const long long stn = (long long)En * 64;
    k_scatter<<<(int)((stn + 255) / 256), 256, 0, stream>>>(ei_neg, flag, dinvn, y_neg,
                                                            out, En);
    const int n4 = N * 16;
    k_clip<<<(n4 + 255) / 256, 256, 0, stream>>>((float4*)out, n4);
  }
}

// Round 15
// 127.760 us; speedup vs baseline: 4.6992x; 4.6992x over previous
//
#include <hip/hip_runtime.h>
#include <stdint.h>
#include <math.h>

#define HID 64
#define RPB 128          // rows per dst bin
#define TBS 1024         // threads per block for build pass
#define EPT 4            // edges per thread in k_build (registers)
#define CAP 2048         // fixed per-bin-segment capacity (lambda~1279, +21 sigma)
#define MAXBINS 2048     // need 2*NBF <= MAXBINS

typedef __attribute__((ext_vector_type(8))) short bf16x8;
typedef __attribute__((ext_vector_type(4))) float f32x4;

// ---------------------------------------------------------------------------
// bf16 helpers (RTNE pack, cheap unpack).
__device__ inline float bf2f(unsigned short u) {
  return __uint_as_float(((unsigned)u) << 16);
}
__device__ inline unsigned short f2bf(float f) {
  unsigned u = __float_as_uint(f);
  unsigned r = u + 0x7FFFu + ((u >> 16) & 1u);
  return (unsigned short)(r >> 16);
}
__device__ inline unsigned pk2(float a, float b) {
  return (unsigned)f2bf(a) | ((unsigned)f2bf(b) << 16);
}

// ---------------------------------------------------------------------------
// Per-block edge-dtype detect (int64 => all high words of first 1024 values
// are 0; int32 random values make that probability ~0). 4 KB read, L2-hot.
__device__ inline bool detect_is64(const unsigned* __restrict__ eiw, int nWords,
                                   unsigned* shflag, int tid) {
  if (tid == 0) *shflag = 0u;
  __syncthreads();
  if (tid < 1024) {
    int w = 2 * tid + 1;
    unsigned v = (w < nWords) ? eiw[w] : 0u;
    if (v) atomicOr(shflag, 1u);
  }
  __syncthreads();
  return (*shflag == 0u);
}

// ---------------------------------------------------------------------------
// Cursor init: binCursor[i] = i * CAP.
__global__ __launch_bounds__(256) void k_initcur(unsigned* __restrict__ cur,
                                                 int nbins) {
  int i = blockIdx.x * 256 + threadIdx.x;
  if (i < nbins) cur[i] = (unsigned)i * CAP;
}

// ---------------------------------------------------------------------------
// Fused build: blocks < nbb read their 4096-edge chunk ONCE into registers,
// build the LDS bin histogram, claim global per-bin bases via one
// atomicAdd(binCursor[bin], cnt) per (block,bin), then scatter packed
// src|(dlocal<<20) records into the bin's fixed-capacity region.
// Blocks >= nbb compute Mbt/cvec (weight fusion).
__global__ __launch_bounds__(TBS) void k_build(
    const void* __restrict__ eip, const void* __restrict__ ein,
    unsigned* __restrict__ binCursor, unsigned* __restrict__ binned,
    int Ep, int En, int NBF, int nbb,
    const float* __restrict__ Wpos, const float* __restrict__ Wneg,
    const float* __restrict__ Wp, const float* __restrict__ Wn,
    const float* __restrict__ bpos, const float* __restrict__ bneg,
    const float* __restrict__ bp, const float* __restrict__ bn,
    unsigned short* __restrict__ Mbt, float* __restrict__ cvec) {
  const int t = threadIdx.x;
  if ((int)blockIdx.x >= nbb) {
    int idx = ((int)blockIdx.x - nbb) * TBS + t;
    if (idx < 4096) {
      int i = idx >> 6, j = idx & 63;
      float a = 0.f, b = 0.f;
      for (int k = 0; k < 64; ++k) {
        a += Wpos[i * 64 + k] * Wp[k * 64 + j];
        b += Wneg[i * 64 + k] * Wn[k * 64 + j];
      }
      Mbt[j * 64 + i] = f2bf(a);
      Mbt[(64 + j) * 64 + i] = f2bf(b);
    }
    if ((int)blockIdx.x == nbb && t < 64) {
      float acc = bp[t] + bn[t];
      for (int k = 0; k < 64; ++k)
        acc += bpos[k] * Wp[k * 64 + t] + bneg[k] * Wn[k * 64 + t];
      cvec[t] = acc;
    }
    return;
  }
  __shared__ unsigned hist[MAXBINS];
  __shared__ unsigned shflag;
  const int nbins = 2 * NBF;
  for (int i = t; i < nbins; i += TBS) hist[i] = 0u;
  const bool is64 = detect_is64((const unsigned*)eip, 2 * Ep, &shflag, t);
  const long long ET = (long long)Ep + En;
  const long long beg = (long long)blockIdx.x * (EPT * TBS);

  int sr[EPT], dr[EPT];
#pragma unroll
  for (int k = 0; k < EPT; ++k) {
    long long e = beg + (long long)k * TBS + t;
    dr[k] = -1;
    if (e < ET) {
      int seg = e >= Ep;
      long long ee = seg ? e - Ep : e;
      const void* ei = seg ? ein : eip;
      long long Ecur = seg ? En : Ep;
      int s, d;
      if (is64) {
        const long long* p = (const long long*)ei;
        s = (int)p[ee]; d = (int)p[Ecur + ee];
      } else {
        const int* p = (const int*)ei;
        s = p[ee]; d = p[Ecur + ee];
      }
      sr[k] = s;
      dr[k] = seg * NBF * RPB + d;  // encode seg via offset (d < NBF*RPB)
      atomicAdd(&hist[dr[k] >> 7], 1u);
    }
  }
  __syncthreads();
  // Claim global bases; hist[i] becomes this block's running global cursor.
  for (int i = t; i < nbins; i += TBS)
    hist[i] = atomicAdd(&binCursor[i], hist[i]);
  __syncthreads();
#pragma unroll
  for (int k = 0; k < EPT; ++k) {
    if (dr[k] >= 0) {
      int idx = dr[k] >> 7;
      unsigned pos = atomicAdd(&hist[idx], 1u);
      if (pos < (unsigned)(idx + 1) * CAP)  // overflow guard (memory safety)
        binned[pos] = (unsigned)sr[k] | ((unsigned)(dr[k] & 127) << 20);
    }
  }
}

// ---------------------------------------------------------------------------
// Binsort: one block per bin — counting-sort both segments by dlocal into the
// bin-strided CSR; emits per-node [start,end) + dinv.
__global__ __launch_bounds__(512) void k_binsort(
    const unsigned* __restrict__ binned, const unsigned* __restrict__ binCursor,
    unsigned* __restrict__ csr,
    unsigned* __restrict__ offsPb, unsigned* __restrict__ offsPe,
    unsigned* __restrict__ offsNb, unsigned* __restrict__ offsNe,
    float* __restrict__ dinvp, float* __restrict__ dinvn, int N, int NBF) {
  __shared__ unsigned cnt[2 * RPB], sc[2 * RPB], cur[2 * RPB];
  const int t = threadIdx.x;
  const int b = blockIdx.x;
  const unsigned sb0 = (unsigned)b * CAP;
  const unsigned se0 = min(binCursor[b], sb0 + CAP);
  const unsigned sb1 = (unsigned)(NBF + b) * CAP;
  const unsigned se1 = min(binCursor[NBF + b], sb1 + CAP);
  if (t < 2 * RPB) cnt[t] = 0u;
  __syncthreads();
  for (unsigned i = sb0 + t; i < se0; i += 512)
    atomicAdd(&cnt[binned[i] >> 20], 1u);
  for (unsigned i = sb1 + t; i < se1; i += 512)
    atomicAdd(&cnt[RPB + (binned[i] >> 20)], 1u);
  __syncthreads();
  if (t < 2 * RPB) sc[t] = cnt[t];
  __syncthreads();
#pragma unroll
  for (int o = 1; o < RPB; o <<= 1) {
    unsigned v = 0u;
    if (t < 2 * RPB && (t & (RPB - 1)) >= o) v = sc[t - o];
    __syncthreads();
    if (t < 2 * RPB) sc[t] += v;
    __syncthreads();
  }
  if (t < 2 * RPB) {
    unsigned excl = sc[t] - cnt[t];
    int seg = t >> 7;
    unsigned start = (seg ? sb1 : sb0) + excl;
    cur[t] = start;
    int g = b * RPB + (t & (RPB - 1));
    if (g < N) {
      if (seg == 0) {
        offsPb[g] = start;
        offsPe[g] = start + cnt[t];
        dinvp[g] = rsqrtf((float)cnt[t] + 1.0f);
      } else {
        offsNb[g] = start;
        offsNe[g] = start + cnt[t];
        dinvn[g] = rsqrtf((float)cnt[t] + 1.0f);
      }
    }
  }
  __syncthreads();
  for (unsigned i = sb0 + t; i < se0; i += 512) {
    unsigned w = binned[i];
    unsigned p = atomicAdd(&cur[w >> 20], 1u);
    csr[p] = w & 0xFFFFFu;
  }
  for (unsigned i = sb1 + t; i < se1; i += 512) {
    unsigned w = binned[i];
    unsigned p = atomicAdd(&cur[RPB + (w >> 20)], 1u);
    csr[p] = w & 0xFFFFFu;
  }
}

// ---------------------------------------------------------------------------
// Fused LayerNorm + dual GEMM via MFMA (bf16 in, fp32 acc), epilogue scales by
// dinv[row], stores bf16. Block = 256 threads = 4 waves, 64 rows.
__global__ __launch_bounds__(256) void k_ln_gemm(
    const float* __restrict__ h, const float* __restrict__ gamma,
    const float* __restrict__ beta, const unsigned short* __restrict__ Mbt,
    const float* __restrict__ dinvp, const float* __restrict__ dinvn,
    unsigned short* __restrict__ yp, unsigned short* __restrict__ yn, int N) {
  __shared__ __align__(16) unsigned short Abf[64][72];
  __shared__ __align__(16) unsigned short Bt[128][72];
  const int t = threadIdx.x;
  const int r0 = blockIdx.x * 64;

#pragma unroll
  for (int i = 0; i < 4; ++i) {
    int f = i * 256 + t;
    int n = f >> 3, c8 = f & 7;
    *(uint4*)(&Bt[n][c8 * 8]) = ((const uint4*)Mbt)[f];
  }

  const int r = t >> 2, p = t & 3;
  float4 va, vb, vc, vd;
  if (r0 + r < N) {
    const float4* hp = (const float4*)(h + (size_t)(r0 + r) * 64 + p * 16);
    va = hp[0]; vb = hp[1]; vc = hp[2]; vd = hp[3];
  } else {
    va = vb = vc = vd = make_float4(0.f, 0.f, 0.f, 0.f);
  }
  float s  = (va.x + va.y + va.z + va.w) + (vb.x + vb.y + vb.z + vb.w) +
             (vc.x + vc.y + vc.z + vc.w) + (vd.x + vd.y + vd.z + vd.w);
  float ss = (va.x*va.x + va.y*va.y + va.z*va.z + va.w*va.w) +
             (vb.x*vb.x + vb.y*vb.y + vb.z*vb.z + vb.w*vb.w) +
             (vc.x*vc.x + vc.y*vc.y + vc.z*vc.z + vc.w*vc.w) +
             (vd.x*vd.x + vd.y*vd.y + vd.z*vd.z + vd.w*vd.w);
  s  += __shfl_xor(s, 1);  ss += __shfl_xor(ss, 1);
  s  += __shfl_xor(s, 2);  ss += __shfl_xor(ss, 2);
  float mu = s * (1.f / 64.f);
  float var = ss * (1.f / 64.f) - mu * mu;
  float rstd = rsqrtf(var + 1e-5f);
  {
    const float4* g4 = (const float4*)(gamma + p * 16);
    const float4* b4 = (const float4*)(beta + p * 16);
    float4 g0 = g4[0], g1 = g4[1], g2 = g4[2], g3 = g4[3];
    float4 e0 = b4[0], e1 = b4[1], e2 = b4[2], e3 = b4[3];
#define LNV(v, g, e) ((v - mu) * rstd * g + e)
    unsigned w0 = pk2(LNV(va.x, g0.x, e0.x), LNV(va.y, g0.y, e0.y));
    unsigned w1 = pk2(LNV(va.z, g0.z, e0.z), LNV(va.w, g0.w, e0.w));
    unsigned w2 = pk2(LNV(vb.x, g1.x, e1.x), LNV(vb.y, g1.y, e1.y));
    unsigned w3 = pk2(LNV(vb.z, g1.z, e1.z), LNV(vb.w, g1.w, e1.w));
    unsigned w4 = pk2(LNV(vc.x, g2.x, e2.x), LNV(vc.y, g2.y, e2.y));
    unsigned w5 = pk2(LNV(vc.z, g2.z, e2.z), LNV(vc.w, g2.w, e2.w));
    unsigned w6 = pk2(LNV(vd.x, g3.x, e3.x), LNV(vd.y, g3.y, e3.y));
    unsigned w7 = pk2(LNV(vd.z, g3.z, e3.z), LNV(vd.w, g3.w, e3.w));
#undef LNV
    *(uint4*)(&Abf[r][p * 16]) = make_uint4(w0, w1, w2, w3);
    *(uint4*)(&Abf[r][p * 16 + 8]) = make_uint4(w4, w5, w6, w7);
  }
  __syncthreads();

  const int w = t >> 6, lane = t & 63;
  const int mrow = lane & 15, grp = lane >> 4;
  bf16x8 a0 = *(const bf16x8*)(&Abf[w * 16 + mrow][grp * 8]);
  bf16x8 a1 = *(const bf16x8*)(&Abf[w * 16 + mrow][32 + grp * 8]);
  float sp[4], sn[4];
#pragma unroll
  for (int reg = 0; reg < 4; ++reg) {
    int grow = r0 + w * 16 + grp * 4 + reg;
    sp[reg] = (grow < N) ? dinvp[grow] : 0.f;
    sn[reg] = (grow < N) ? dinvn[grow] : 0.f;
  }
#pragma unroll
  for (int ct = 0; ct < 8; ++ct) {
    const int n = ct * 16 + mrow;
    bf16x8 b0 = *(const bf16x8*)(&Bt[n][grp * 8]);
    bf16x8 b1 = *(const bf16x8*)(&Bt[n][32 + grp * 8]);
    f32x4 acc = {0.f, 0.f, 0.f, 0.f};
    acc = __builtin_amdgcn_mfma_f32_16x16x32_bf16(a0, b0, acc, 0, 0, 0);
    acc = __builtin_amdgcn_mfma_f32_16x16x32_bf16(a1, b1, acc, 0, 0, 0);
#pragma unroll
    for (int reg = 0; reg < 4; ++reg) {
      int grow = r0 + w * 16 + grp * 4 + reg;
      if (grow < N) {
        if (ct < 4)
          yp[(size_t)grow * 64 + ct * 16 + mrow] = f2bf(sp[reg] * acc[reg]);
        else
          yn[(size_t)grow * 64 + (ct - 4) * 16 + mrow] = f2bf(sn[reg] * acc[reg]);
      }
    }
  }
}

// ---------------------------------------------------------------------------
// Gather (round-9 proven form): one wave per dst node, FOUR 16-lane groups,
// uint2/lane, 2-deep unroll -> 8 rows in flight. All __shfl execute
// wave-uniformly with clamped source index (ds_bpermute from EXEC-inactive
// source lane is undefined); only loads/accumulates are predicated.
// CSR is bin-strided: per-node [start,end) arrays.
__global__ __launch_bounds__(256) void k_gather(
    const unsigned* __restrict__ offsPb, const unsigned* __restrict__ offsPe,
    const unsigned* __restrict__ offsNb, const unsigned* __restrict__ offsNe,
    const unsigned* __restrict__ csr, const float* __restrict__ dinvp,
    const float* __restrict__ dinvn, const unsigned short* __restrict__ yp,
    const unsigned short* __restrict__ yn, const float* __restrict__ cvec,
    float* __restrict__ out, int N) {
  const int lane = threadIdx.x & 63;
  const int grp = lane >> 4;
  const int lc = lane & 15;
  const int d = (int)(((long long)blockIdx.x * 256 + threadIdx.x) >> 6);
  if (d >= N) return;

  float4 ap = make_float4(0.f, 0.f, 0.f, 0.f);
  float4 an = make_float4(0.f, 0.f, 0.f, 0.f);

#define ACC4(ACC, U)                                                         \
  ACC.x += bf2f((unsigned short)(U.x & 0xFFFFu));                            \
  ACC.y += bf2f((unsigned short)(U.x >> 16));                                \
  ACC.z += bf2f((unsigned short)(U.y & 0xFFFFu));                            \
  ACC.w += bf2f((unsigned short)(U.y >> 16));

#define GATHER_SEG(OFFB, OFFE, Y, ACC)                                       \
  {                                                                          \
    unsigned beg = OFFB[d], end = OFFE[d];                                   \
    for (unsigned base = beg; base < end; base += 64u) {                     \
      int m = (int)min(64u, end - base);                                     \
      int idx = (base + (unsigned)lane < end) ? (int)csr[base + lane] : 0;   \
      int j = 0;                                                             \
      for (; j + 7 < m; j += 8) {                                            \
        int s0 = __shfl(idx, j + grp);                                       \
        int s1 = __shfl(idx, j + 4 + grp);                                   \
        uint2 u0 = *(const uint2*)(Y + (size_t)s0 * 64 + 4 * lc);            \
        uint2 u1 = *(const uint2*)(Y + (size_t)s1 * 64 + 4 * lc);            \
        ACC4(ACC, u0)                                                        \
        ACC4(ACC, u1)                                                        \
      }                                                                      \
      for (; j < m; j += 4) {                                                \
        int e = j + grp;                                                     \
        int es = (e < m) ? e : (m - 1);  /* clamp: source lane stays valid */\
        int s0 = __shfl(idx, es);        /* executed by ALL lanes */         \
        if (e < m) {                                                         \
          uint2 u0 = *(const uint2*)(Y + (size_t)s0 * 64 + 4 * lc);          \
          ACC4(ACC, u0)                                                      \
        }                                                                    \
      }                                                                      \
    }                                                                        \
  }

  GATHER_SEG(offsPb, offsPe, yp, ap)
  GATHER_SEG(offsNb, offsNe, yn, an)
#undef GATHER_SEG

  ap.x += __shfl_xor(ap.x, 16); ap.y += __shfl_xor(ap.y, 16);
  ap.z += __shfl_xor(ap.z, 16); ap.w += __shfl_xor(ap.w, 16);
  an.x += __shfl_xor(an.x, 16); an.y += __shfl_xor(an.y, 16);
  an.z += __shfl_xor(an.z, 16); an.w += __shfl_xor(an.w, 16);
  ap.x += __shfl_xor(ap.x, 32); ap.y += __shfl_xor(ap.y, 32);
  ap.z += __shfl_xor(ap.z, 32); ap.w += __shfl_xor(ap.w, 32);
  an.x += __shfl_xor(an.x, 32); an.y += __shfl_xor(an.y, 32);
  an.z += __shfl_xor(an.z, 32); an.w += __shfl_xor(an.w, 32);

  if (lane < 16) {
    uint2 up = *(const uint2*)(yp + (size_t)d * 64 + 4 * lc);
    uint2 un = *(const uint2*)(yn + (size_t)d * 64 + 4 * lc);
    ap.x += bf2f((unsigned short)(up.x & 0xFFFFu));
    ap.y += bf2f((unsigned short)(up.x >> 16));
    ap.z += bf2f((unsigned short)(up.y & 0xFFFFu));
    ap.w += bf2f((unsigned short)(up.y >> 16));
    an.x += bf2f((unsigned short)(un.x & 0xFFFFu));
    an.y += bf2f((unsigned short)(un.x >> 16));
    an.z += bf2f((unsigned short)(un.y & 0xFFFFu));
    an.w += bf2f((unsigned short)(un.y >> 16));
    float dp = dinvp[d], dn = dinvn[d];
    float4 cc = *(const float4*)(cvec + 4 * lc);
    float4 v;
    v.x = fminf(fmaxf(cc.x + dp * ap.x + dn * an.x, -50.f), 50.f);
    v.y = fminf(fmaxf(cc.y + dp * ap.y + dn * an.y, -50.f), 50.f);
    v.z = fminf(fmaxf(cc.z + dp * ap.z + dn * an.z, -50.f), 50.f);
    v.w = fminf(fmaxf(cc.w + dp * ap.w + dn * an.w, -50.f), 50.f);
    *(float4*)(out + (size_t)d * 64 + 4 * lc) = v;
  }
#undef ACC4
}

// ---------------------------------------------------------------------------
// Fallback path (atomic scatter), bf16 y pre-scaled by dinv[src].
__global__ __launch_bounds__(256) void k_prep(
    const float* __restrict__ Wpos, const float* __restrict__ Wneg,
    const float* __restrict__ Wp, const float* __restrict__ Wn,
    const float* __restrict__ bpos, const float* __restrict__ bneg,
    const float* __restrict__ bp, const float* __restrict__ bn,
    unsigned short* __restrict__ Mbt, float* __restrict__ cvec,
    const unsigned* __restrict__ eiw, unsigned* __restrict__ flag, int nWords) {
  if (blockIdx.x == 16) {
    __shared__ unsigned acc;
    if (threadIdx.x == 0) acc = 0u;
    __syncthreads();
    unsigned bad = 0u;
    for (int i = 0; i < 4; ++i) {
      int w = (i * 256 + (int)threadIdx.x) * 2 + 1;
      if (w < nWords) bad |= eiw[w];
    }
    if (bad) atomicOr(&acc, 1u);
    __syncthreads();
    if (threadIdx.x == 0) *flag = (acc == 0u) ? 1u : 0u;
    return;
  }
  int idx = blockIdx.x * 256 + threadIdx.x;
  int i = idx >> 6, j = idx & 63;
  float a = 0.f, b = 0.f;
  for (int k = 0; k < 64; ++k) {
    a += Wpos[i * 64 + k] * Wp[k * 64 + j];
    b += Wneg[i * 64 + k] * Wn[k * 64 + j];
  }
  Mbt[j * 64 + i] = f2bf(a);
  Mbt[(64 + j) * 64 + i] = f2bf(b);
  if (blockIdx.x == 0 && threadIdx.x < 64) {
    int jj = threadIdx.x;
    float acc = bp[jj] + bn[jj];
    for (int k = 0; k < 64; ++k)
      acc += bpos[k] * Wp[k * 64 + jj] + bneg[k] * Wn[k * 64 + jj];
    cvec[jj] = acc;
  }
}

__global__ __launch_bounds__(256) void k_deg(const void* __restrict__ ei,
                                             const unsigned* __restrict__ flag,
                                             float* __restrict__ deg, int E) {
  int e = blockIdx.x * 256 + threadIdx.x;
  if (e >= E) return;
  long long d;
  if (*flag) d = ((const long long*)ei)[(long long)E + e];
  else       d = (long long)((const int*)ei)[(long long)E + e];
  atomicAdd(&deg[(int)d], 1.0f);
}

__global__ __launch_bounds__(256) void k_dinv(float* __restrict__ degp,
                                              float* __restrict__ degn, int N) {
  int i = blockIdx.x * 256 + threadIdx.x;
  if (i < N) {
    degp[i] = rsqrtf(degp[i] + 1.0f);
    degn[i] = rsqrtf(degn[i] + 1.0f);
  }
}

__global__ __launch_bounds__(256) void k_init_out(
    const unsigned short* __restrict__ yp, const unsigned short* __restrict__ yn,
    const float* __restrict__ dinvp, const float* __restrict__ dinvn,
    const float* __restrict__ cvec, float* __restrict__ out, long long n) {
  long long i = (long long)blockIdx.x * 256 + threadIdx.x;
  if (i >= n) return;
  int row = (int)(i >> 6), col = (int)(i & 63);
  out[i] = cvec[col] + dinvp[row] * bf2f(yp[i]) + dinvn[row] * bf2f(yn[i]);
}

__global__ __launch_bounds__(256) void k_scatter(
    const void* __restrict__ ei, const unsigned* __restrict__ flag,
    const float* __restrict__ dinv, const unsigned short* __restrict__ y,
    float* __restrict__ out, int E) {
  const int lane = threadIdx.x & 63;
  long long e = ((long long)blockIdx.x * 256 + threadIdx.x) >> 6;
  if (e >= E) return;
  long long s, d;
  if (*flag) {
    const long long* p = (const long long*)ei;
    s = p[e]; d = p[E + e];
  } else {
    const int* p = (const int*)ei;
    s = (long long)p[e]; d = (long long)p[E + e];
  }
  float v = dinv[(int)d] * bf2f(y[s * 64 + lane]);
  atomicAdd(out + d * 64 + lane, v);
}

__global__ __launch_bounds__(256) void k_clip(float4* __restrict__ out, int n4) {
  int i = blockIdx.x * 256 + threadIdx.x;
  if (i >= n4) return;
  float4 v = out[i];
  v.x = fminf(fmaxf(v.x, -50.f), 50.f);
  v.y = fminf(fmaxf(v.y, -50.f), 50.f);
  v.z = fminf(fmaxf(v.z, -50.f), 50.f);
  v.w = fminf(fmaxf(v.w, -50.f), 50.f);
  out[i] = v;
}

// ---------------------------------------------------------------------------
extern "C" void kernel_launch(void* const* d_in, const int* in_sizes, int n_in,
                              void* d_out, int out_size, void* d_ws, size_t ws_size,
                              hipStream_t stream) {
  const float* h      = (const float*)d_in[1];
  const void*  ei_pos = d_in[2];
  const void*  ei_neg = d_in[3];
  const float* gamma  = (const float*)d_in[4];
  const float* beta   = (const float*)d_in[5];
  const float* W_pos  = (const float*)d_in[6];
  const float* b_pos  = (const float*)d_in[7];
  const float* W_neg  = (const float*)d_in[8];
  const float* b_neg  = (const float*)d_in[9];
  const float* Wp     = (const float*)d_in[10];
  const float* bp     = (const float*)d_in[11];
  const float* Wn     = (const float*)d_in[12];
  const float* bn     = (const float*)d_in[13];
  float* out = (float*)d_out;

  const int N = in_sizes[1] / HID;
  const int Ep = in_sizes[2] / 2;
  const int En = in_sizes[3] / 2;
  const int NBF = (N + RPB - 1) / RPB;
  const int nbins = 2 * NBF;
  const long long ET = (long long)Ep + En;
  const int nbb = (int)((ET + (long long)EPT * TBS - 1) / ((long long)EPT * TBS));

  float* ws = (float*)d_ws;
  size_t off = 0;
  auto alloc = [&](size_t nf) {
    float* p = ws + off;
    off = (off + nf + 63) & ~(size_t)63;
    return p;
  };
  // Common arrays.
  unsigned short* y_pos = (unsigned short*)alloc((size_t)N * HID / 2);
  unsigned short* y_neg = (unsigned short*)alloc((size_t)N * HID / 2);
  float* dinvp = alloc(N);
  float* dinvn = alloc(N);
  unsigned short* Mbt = (unsigned short*)alloc(128 * 64 / 2);
  float* cvec  = alloc(64);
  unsigned* flag = (unsigned*)alloc(64);
  // Fast-path arrays (fixed-capacity bins; no scan needed).
  unsigned* binCursor = (unsigned*)alloc(nbins);
  unsigned* offsPb = (unsigned*)alloc(N);
  unsigned* offsPe = (unsigned*)alloc(N);
  unsigned* offsNb = (unsigned*)alloc(N);
  unsigned* offsNe = (unsigned*)alloc(N);
  unsigned* binned = (unsigned*)alloc((size_t)nbins * CAP);
  unsigned* csr    = (unsigned*)alloc((size_t)nbins * CAP);
  // Poisson capacity check PER SEGMENT PER BIN: lambda = maxE/NBF must satisfy
  // lambda + 20*sqrt(lambda) + 8 <= CAP (round-14 gate bug: compared totals).
  const double lam = (double)(Ep > En ? Ep : En) / (double)NBF;
  const bool capOk = lam + 20.0 * sqrt(lam + 1.0) + 8.0 <= (double)CAP;
  const bool fast = (off * sizeof(float) <= ws_size) && (nbins <= MAXBINS) &&
                    (N < (1 << 20)) && capOk && (nbb >= 1);

  if (fast) {
    k_initcur<<<(nbins + 255) / 256, 256, 0, stream>>>(binCursor, nbins);
    k_build<<<nbb + 4, TBS, 0, stream>>>(
        ei_pos, ei_neg, binCursor, binned, Ep, En, NBF, nbb,
        W_pos, W_neg, Wp, Wn, b_pos, b_neg, bp, bn, Mbt, cvec);
    k_binsort<<<NBF, 512, 0, stream>>>(binned, binCursor, csr,
                                       offsPb, offsPe, offsNb, offsNe,
                                       dinvp, dinvn, N, NBF);
    k_ln_gemm<<<(N + 63) / 64, 256, 0, stream>>>(h, gamma, beta, Mbt, dinvp, dinvn,
                                                 y_pos, y_neg, N);
    const long long gthreads = (long long)N * 64;
    k_gather<<<(int)((gthreads + 255) / 256), 256, 0, stream>>>(
        offsPb, offsPe, offsNb, offsNe, csr, dinvp, dinvn,
        y_pos, y_neg, cvec, out, N);
  } else {
    k_prep<<<17, 256, 0, stream>>>(W_pos, W_neg, Wp, Wn, b_pos, b_neg, bp, bn,
                                   Mbt, cvec, (const unsigned*)ei_pos, flag, 2 * Ep);
    hipMemsetAsync(dinvp, 0, sizeof(float) * N, stream);
    hipMemsetAsync(dinvn, 0, sizeof(float) * N, stream);
    k_deg<<<(Ep + 255) / 256, 256, 0, stream>>>(ei_pos, flag, dinvp, Ep);
    k_deg<<<(En + 255) / 256, 256, 0, stream>>>(ei_neg, flag, dinvn, En);
    k_dinv<<<(N + 255) / 256, 256, 0, stream>>>(dinvp, dinvn, N);
    k_ln_gemm<<<(N + 63) / 64, 256, 0, stream>>>(h, gamma, beta, Mbt, dinvp, dinvn,
                                                 y_pos, y_neg, N);
    const long long n = (long long)N * 64;
    k_init_out<<<(int)((n + 255) / 256), 256, 0, stream>>>(y_pos, y_neg, dinvp, dinvn,
                                                           cvec, out, n);
    const long long st = (long long)Ep * 64;
    k_scatter<<<(int)((st + 255) / 256), 256, 0, stream>>>(ei_pos, flag, dinvp, y_pos,
                                                           out, Ep);
    const long long stn = (long long)En * 64;
    k_scatter<<<(int)((stn + 255) / 256), 256, 0, stream>>>(ei_neg, flag, dinvn, y_neg,
                                                            out, En);
    const int n4 = N * 16;
    k_clip<<<(n4 + 255) / 256, 256, 0, stream>>>((float4*)out, n4);
  }
}